// Round 7
// baseline (121.587 us; speedup 1.0000x reference)
//
#include <hip/hip_runtime.h>
#include <hip/hip_bf16.h>

#define N_NODES 8192
#define N_EDGES 131072
#define LN_EPS  1e-5f

typedef __attribute__((ext_vector_type(8))) short bf16x8;
typedef __attribute__((ext_vector_type(4))) float f32x4;

// silu via v_rcp_f32: avoids IEEE div expansion (no fast-math in harness)
__device__ __forceinline__ float silu_f(float x) {
    return x * __builtin_amdgcn_rcpf(1.0f + __expf(-x));
}

// fp32 -> bf16 RNE (scalar)
__device__ __forceinline__ unsigned short f2bf(float x) {
    union { float f; unsigned int u; } v; v.f = x;
    unsigned int r = v.u + 0x7FFFu + ((v.u >> 16) & 1u);
    return (unsigned short)(r >> 16);
}
__device__ __forceinline__ float bf2f(unsigned short u) {
    union { float f; unsigned int x; } v; v.x = ((unsigned int)u) << 16;
    return v.f;
}
// fp32 pair -> packed bf16x2 via v_cvt_pk_bf16_f32
__device__ __forceinline__ unsigned int pk2(float a, float b) {
    float2 t; t.x = a; t.y = b;
    union { __hip_bfloat162 h; unsigned int u; } v;
    v.h = __float22bfloat162_rn(t);
    return v.u;
}
__device__ __forceinline__ bf16x8 pack8(float4 u, float4 v) {
    union { bf16x8 b; unsigned int w[4]; } o;
    o.w[0] = pk2(u.x, u.y); o.w[1] = pk2(u.z, u.w);
    o.w[2] = pk2(v.x, v.y); o.w[3] = pk2(v.z, v.w);
    return o.b;
}
__device__ __forceinline__ f32x4 mfma16(bf16x8 a, bf16x8 b, f32x4 c) {
    return __builtin_amdgcn_mfma_f32_16x16x32_bf16(a, b, c, 0, 0, 0);
}

// ---------------------------------------------------------------------------
// Kernel 0: weight prep.
//   Wtw  [n][r] = ln_g[r] * W_w[r][n]   (LN gain folded in)
//   bwf  [n]    = b_w[n] + sum_r ln_b[r] * W_w[r][n]  (LN bias folded in)
//   Wt1b/Wt2b   = W_t1^T / W_t2^T (n-major), Wqt/Wk*t = W_v*^T (r-major)
// ---------------------------------------------------------------------------
__global__ __launch_bounds__(256) void prep_kernel(
    const float* __restrict__ W_w, const float* __restrict__ W_t1,
    const float* __restrict__ W_t2, const float* __restrict__ Wvq,
    const float* __restrict__ Wvk0, const float* __restrict__ Wvk1,
    const float* __restrict__ Wvk2, const float* __restrict__ ln_g,
    const float* __restrict__ ln_b, const float* __restrict__ b_w,
    unsigned short* __restrict__ Wtw, unsigned short* __restrict__ Wt1b,
    unsigned short* __restrict__ Wt2b, unsigned short* __restrict__ Wqt,
    unsigned short* __restrict__ Wk0t, unsigned short* __restrict__ Wk1t,
    unsigned short* __restrict__ Wk2t, float* __restrict__ bwf)
{
    int i = blockIdx.x * 256 + threadIdx.x;
    if (i < 16384) {
        int n = i >> 7, k = i & 127;
        Wt1b[i] = f2bf(W_t1[k * 128 + n]);
        Wt2b[i] = f2bf(W_t2[k * 128 + n]);
    }
    if (i < 4096) {
        { int n = i >> 5, r = i & 31; Wtw[i] = f2bf(ln_g[r] * W_w[r * 128 + n]); }
        int r = i >> 7, d = i & 127;
        Wqt[i]  = f2bf(Wvq [d * 32 + r]);
        Wk0t[i] = f2bf(Wvk0[d * 32 + r]);
        Wk1t[i] = f2bf(Wvk1[d * 32 + r]);
        Wk2t[i] = f2bf(Wvk2[d * 32 + r]);
    }
    if (blockIdx.x == 0 && threadIdx.x < 128) {
        const int n = threadIdx.x;
        float acc = b_w[n];
        #pragma unroll
        for (int r = 0; r < 32; ++r) acc += ln_b[r] * W_w[r * 128 + n];
        bwf[n] = acc;
    }
}

// ---------------------------------------------------------------------------
// Kernel 1: MFMA projections — barrier-free, no LDS.
// Output layout [n][r][l-pad16] bf16 (512 per node): edge gather reads 16B
// chunks per (node, r).
// ---------------------------------------------------------------------------
template<int S, int LOFF>
__device__ __forceinline__ void proj_body(
    const float* __restrict__ X, const unsigned short* __restrict__ Wqt,
    const unsigned short* __restrict__ Wkt,
    unsigned short* __restrict__ eq, unsigned short* __restrict__ ek,
    int row0)
{
    const int tid  = threadIdx.x;
    const int lane = tid & 63;
    const int wv   = tid >> 6;
    const int l15  = lane & 15;
    const int lk   = lane >> 4;
    const int xrow = row0 + wv * 16 + l15;

    bf16x8 xf[4];
    #pragma unroll
    for (int kt = 0; kt < 4; ++kt) {
        const float* p = X + (size_t)xrow * 128 + kt * 32 + lk * 8;
        xf[kt] = pack8(*(const float4*)p, *(const float4*)(p + 4));
    }

    f32x4 qa[2], ka[2];
    #pragma unroll
    for (int h = 0; h < 2; ++h) {
        qa[h] = (f32x4){0.f, 0.f, 0.f, 0.f};
        ka[h] = (f32x4){0.f, 0.f, 0.f, 0.f};
    }
    #pragma unroll
    for (int kt = 0; kt < 4; ++kt) {
        #pragma unroll
        for (int h = 0; h < 2; ++h) {
            bf16x8 wq = *(const bf16x8*)&Wqt[(h * 16 + l15) * 128 + kt * 32 + lk * 8];
            bf16x8 wk = *(const bf16x8*)&Wkt[(h * 16 + l15) * 128 + kt * 32 + lk * 8];
            qa[h] = mfma16(wq, xf[kt], qa[h]);
            ka[h] = mfma16(wk, xf[kt], ka[h]);
        }
    }

    const int n = xrow / S;
    const int l = xrow % S + LOFF;
    const size_t base = (size_t)n * 512 + l;   // [n][r][l16]
    #pragma unroll
    for (int h = 0; h < 2; ++h) {
        #pragma unroll
        for (int j = 0; j < 4; ++j) {
            const int r = h * 16 + lk * 4 + j;
            eq[base + r * 16] = f2bf(qa[h][j]);
            ek[base + r * 16] = f2bf(ka[h][j]);
        }
    }
}

__global__ __launch_bounds__(256) void proj_kernel(
    const float* __restrict__ X0, const float* __restrict__ X1,
    const float* __restrict__ X2,
    const unsigned short* __restrict__ Wqt,
    const unsigned short* __restrict__ Wk0t,
    const unsigned short* __restrict__ Wk1t,
    const unsigned short* __restrict__ Wk2t,
    unsigned short* __restrict__ eq, unsigned short* __restrict__ ek)
{
    const int b = blockIdx.x;
    if (b < 384)
        proj_body<3, 0>(X0, Wqt, Wk0t, eq, ek, b * 64);
    else if (b < 1024)
        proj_body<5, 3>(X1, Wqt, Wk1t, eq, ek, (b - 384) * 64);
    else
        proj_body<7, 8>(X2, Wqt, Wk2t, eq, ek, (b - 1024) * 64);
}

// ---------------------------------------------------------------------------
// Kernel 2: FUSED edge pipeline. 4 waves x 64 edges, barrier-free.
//  Phase W (lane = edge): gather eq[ni]/ek[nj] ([n][r][l16]), per-degree
//    w_r = q.k - (q.r)(k.r)(2-r.r); lane-local LayerNorm (g/b pre-folded);
//    bf16 wn -> 5KB LDS panel (pad-40 rows) -> dw B-frags; fenced, then
//    panel space is reused by the h panel.
//  GEMM1/GEMM2/dw/epilogue: as round 6 (weights = A, edges = B, D[n][edge]).
// ---------------------------------------------------------------------------
__global__ __launch_bounds__(256) void edge_kernel(
    const float* __restrict__ t_ij,
    const unsigned short* __restrict__ eq, const unsigned short* __restrict__ ek,
    const float* __restrict__ r0, const float* __restrict__ r1,
    const float* __restrict__ r2, const int* __restrict__ eidx,
    const unsigned short* __restrict__ Wtw, const float* __restrict__ bwf,
    const unsigned short* __restrict__ Wt1, const float* __restrict__ b_t1,
    const unsigned short* __restrict__ Wt2, const float* __restrict__ b_t2,
    float* __restrict__ out)
{
    __shared__ __align__(16) unsigned short Hp[4][64 * 128];  // 16KB per wave

    const int tid  = threadIdx.x;
    const int lane = tid & 63;
    const int wv   = tid >> 6;
    const int l15  = lane & 15;
    const int lk   = lane >> 4;
    const int tile = (blockIdx.x * 4 + wv) * 64;
    char* hp = (char*)&Hp[wv][0];
    const int swz = (l15 & 7) << 4;

    // ================= Phase W: per-lane edge wn =================
    const int e  = tile + lane;
    const int nj = eidx[e];
    const int ni = eidx[N_EDGES + e];

    float rv[15];
    #pragma unroll
    for (int c = 0; c < 3; ++c) rv[c]     = r0[e * 3 + c];
    #pragma unroll
    for (int c = 0; c < 5; ++c) rv[3 + c] = r1[e * 5 + c];
    #pragma unroll
    for (int c = 0; c < 7; ++c) rv[8 + c] = r2[e * 7 + c];
    float c0 = 2.f, c1 = 2.f, c2 = 2.f;
    #pragma unroll
    for (int l = 0; l < 3; ++l)  c0 -= rv[l] * rv[l];
    #pragma unroll
    for (int l = 3; l < 8; ++l)  c1 -= rv[l] * rv[l];
    #pragma unroll
    for (int l = 8; l < 15; ++l) c2 -= rv[l] * rv[l];

    const unsigned short* qbase = eq + (size_t)ni * 512;
    const unsigned short* kbase = ek + (size_t)nj * 512;

    float w[32];
    #pragma unroll
    for (int r = 0; r < 32; ++r) {
        bf16x8 q0 = *(const bf16x8*)(qbase + r * 16);
        bf16x8 q1 = *(const bf16x8*)(qbase + r * 16 + 8);
        bf16x8 k0 = *(const bf16x8*)(kbase + r * 16);
        bf16x8 k1 = *(const bf16x8*)(kbase + r * 16 + 8);
        float qv[15], kv[15];
        #pragma unroll
        for (int l = 0; l < 8; ++l) {
            qv[l] = bf2f((unsigned short)q0[l]);
            kv[l] = bf2f((unsigned short)k0[l]);
        }
        #pragma unroll
        for (int l = 8; l < 15; ++l) {
            qv[l] = bf2f((unsigned short)q1[l - 8]);
            kv[l] = bf2f((unsigned short)k1[l - 8]);
        }
        float qk = 0.f;
        #pragma unroll
        for (int l = 0; l < 15; ++l) qk = fmaf(qv[l], kv[l], qk);
        float dq0 = 0.f, dk0 = 0.f, dq1 = 0.f, dk1 = 0.f, dq2 = 0.f, dk2 = 0.f;
        #pragma unroll
        for (int l = 0; l < 3; ++l)  { dq0 = fmaf(qv[l], rv[l], dq0); dk0 = fmaf(kv[l], rv[l], dk0); }
        #pragma unroll
        for (int l = 3; l < 8; ++l)  { dq1 = fmaf(qv[l], rv[l], dq1); dk1 = fmaf(kv[l], rv[l], dk1); }
        #pragma unroll
        for (int l = 8; l < 15; ++l) { dq2 = fmaf(qv[l], rv[l], dq2); dk2 = fmaf(kv[l], rv[l], dk2); }
        w[r] = qk - dq0 * dk0 * c0 - dq1 * dk1 * c1 - dq2 * dk2 * c2;
    }

    float s = 0.f, s2 = 0.f;
    #pragma unroll
    for (int r = 0; r < 32; ++r) { s += w[r]; s2 += w[r] * w[r]; }
    const float mu   = s * (1.f / 32.f);
    const float var  = s2 * (1.f / 32.f) - mu * mu;
    const float rstd = rsqrtf(var + LN_EPS);

    // wn panel: row = local edge (pad 40 ushorts = 80B -> 2-way-only conflicts)
    #pragma unroll
    for (int p = 0; p < 8; ++p) {
        uint2 pp;
        pp.x = pk2((w[4*p+0] - mu) * rstd, (w[4*p+1] - mu) * rstd);
        pp.y = pk2((w[4*p+2] - mu) * rstd, (w[4*p+3] - mu) * rstd);
        *(uint2*)(hp + lane * 80 + p * 8) = pp;
    }
    bf16x8 wnf[4];
    #pragma unroll
    for (int rt = 0; rt < 4; ++rt)
        wnf[rt] = *(const bf16x8*)(hp + (rt * 16 + l15) * 80 + lk * 16);
    // fence: panel reads must land before Hp writes reuse this space
    asm volatile("s_waitcnt lgkmcnt(0)" ::: "memory");
    __builtin_amdgcn_sched_barrier(0);

    // ================= t-path =================
    bf16x8 a1[4][4];
    #pragma unroll
    for (int kt = 0; kt < 4; ++kt)
        #pragma unroll
        for (int rt = 0; rt < 4; ++rt) {
            const float* p = t_ij + (size_t)(tile + rt * 16 + l15) * 128
                           + kt * 32 + lk * 8;
            a1[kt][rt] = pack8(*(const float4*)p, *(const float4*)(p + 4));
        }

    // ---- GEMM1: h = silu(t @ W_t1 + b_t1) -> D[n][edge] -> h panel ----
    #pragma unroll
    for (int ct = 0; ct < 8; ++ct) {
        bf16x8 w1f[4];
        #pragma unroll
        for (int kt = 0; kt < 4; ++kt)
            w1f[kt] = *(const bf16x8*)&Wt1[(size_t)(ct * 16 + l15) * 128
                                           + kt * 32 + lk * 8];
        f32x4 ac[4];
        #pragma unroll
        for (int rt = 0; rt < 4; ++rt) ac[rt] = (f32x4){0.f, 0.f, 0.f, 0.f};
        #pragma unroll
        for (int kt = 0; kt < 4; ++kt)
            #pragma unroll
            for (int rt = 0; rt < 4; ++rt)
                ac[rt] = mfma16(w1f[kt], a1[kt][rt], ac[rt]);

        const float4 bt1 = *(const float4*)&b_t1[ct * 16 + lk * 4];
        #pragma unroll
        for (int rt = 0; rt < 4; ++rt) {
            uint2 hh;
            hh.x = pk2(silu_f(ac[rt][0] + bt1.x), silu_f(ac[rt][1] + bt1.y));
            hh.y = pk2(silu_f(ac[rt][2] + bt1.z), silu_f(ac[rt][3] + bt1.w));
            *(uint2*)(hp + (((rt * 16 + l15) * 256 + ct * 32 + lk * 8) ^ swz)) = hh;
        }
    }

    // ---- a2 B-frags from h panel (wave-local; compiler inserts lgkmcnt) ----
    bf16x8 a2[4][4];
    #pragma unroll
    for (int kt = 0; kt < 4; ++kt)
        #pragma unroll
        for (int rt = 0; rt < 4; ++rt)
            a2[kt][rt] = *(const bf16x8*)(hp +
                (((rt * 16 + l15) * 256 + kt * 64 + lk * 16) ^ swz));

    // ---- GEMM2 + dw + epilogue ----
    #pragma unroll
    for (int ct = 0; ct < 8; ++ct) {
        bf16x8 w2f[4];
        #pragma unroll
        for (int kt = 0; kt < 4; ++kt)
            w2f[kt] = *(const bf16x8*)&Wt2[(size_t)(ct * 16 + l15) * 128
                                           + kt * 32 + lk * 8];
        bf16x8 wwf = *(const bf16x8*)&Wtw[(ct * 16 + l15) * 32 + lk * 8];

        f32x4 o[4], d[4];
        #pragma unroll
        for (int rt = 0; rt < 4; ++rt) o[rt] = (f32x4){0.f, 0.f, 0.f, 0.f};
        #pragma unroll
        for (int kt = 0; kt < 4; ++kt)
            #pragma unroll
            for (int rt = 0; rt < 4; ++rt)
                o[rt] = mfma16(w2f[kt], a2[kt][rt], o[rt]);
        #pragma unroll
        for (int rt = 0; rt < 4; ++rt)
            d[rt] = mfma16(wwf, wnf[rt], (f32x4){0.f, 0.f, 0.f, 0.f});

        const float4 bwv = *(const float4*)&bwf[ct * 16 + lk * 4];
        const float4 b2v = *(const float4*)&b_t2[ct * 16 + lk * 4];
        #pragma unroll
        for (int rt = 0; rt < 4; ++rt) {
            float4 so;
            so.x = (d[rt][0] + bwv.x) * silu_f(o[rt][0] + b2v.x);
            so.y = (d[rt][1] + bwv.y) * silu_f(o[rt][1] + b2v.y);
            so.z = (d[rt][2] + bwv.z) * silu_f(o[rt][2] + b2v.z);
            so.w = (d[rt][3] + bwv.w) * silu_f(o[rt][3] + b2v.w);
            *(float4*)&out[(size_t)(tile + rt * 16 + l15) * 128 + ct * 16 + lk * 4] = so;
        }
    }
}

extern "C" void kernel_launch(void* const* d_in, const int* in_sizes, int n_in,
                              void* d_out, int out_size, void* d_ws, size_t ws_size,
                              hipStream_t stream) {
    (void)in_sizes; (void)n_in; (void)out_size; (void)ws_size;
    const float* X0   = (const float*)d_in[0];
    const float* X1   = (const float*)d_in[1];
    const float* X2   = (const float*)d_in[2];
    const float* t_ij = (const float*)d_in[3];
    const float* r0   = (const float*)d_in[4];
    const float* r1   = (const float*)d_in[5];
    const float* r2   = (const float*)d_in[6];
    const int*   eidx = (const int*)d_in[7];
    const float* Wvq  = (const float*)d_in[8];
    const float* Wvk0 = (const float*)d_in[9];
    const float* Wvk1 = (const float*)d_in[10];
    const float* Wvk2 = (const float*)d_in[11];
    const float* ln_g = (const float*)d_in[12];
    const float* ln_b = (const float*)d_in[13];
    const float* W_w  = (const float*)d_in[14];
    const float* b_w  = (const float*)d_in[15];
    const float* W_t1 = (const float*)d_in[16];
    const float* b_t1 = (const float*)d_in[17];
    const float* W_t2 = (const float*)d_in[18];
    const float* b_t2 = (const float*)d_in[19];
    float* out = (float*)d_out;

    unsigned short* eq   = (unsigned short*)d_ws;          // [N][32][16] bf16
    unsigned short* ek   = eq  + (size_t)N_NODES * 512;
    unsigned short* Wtw  = ek  + (size_t)N_NODES * 512;    // [128][32] bf16 (g-folded)
    unsigned short* Wt1b = Wtw  + 4096;
    unsigned short* Wt2b = Wt1b + 16384;
    unsigned short* Wqt  = Wt2b + 16384;
    unsigned short* Wk0t = Wqt  + 4096;
    unsigned short* Wk1t = Wk0t + 4096;
    unsigned short* Wk2t = Wk1t + 4096;
    float*          bwf  = (float*)(Wk2t + 4096);          // [128] f32 (b folded)

    prep_kernel<<<64, 256, 0, stream>>>(W_w, W_t1, W_t2, Wvq, Wvk0, Wvk1, Wvk2,
                                        ln_g, ln_b, b_w,
                                        Wtw, Wt1b, Wt2b, Wqt, Wk0t, Wk1t, Wk2t,
                                        bwf);
    proj_kernel<<<1920, 256, 0, stream>>>(X0, X1, X2, Wqt, Wk0t, Wk1t, Wk2t,
                                          eq, ek);
    edge_kernel<<<N_EDGES / 256, 256, 0, stream>>>(t_ij, eq, ek, r0, r1, r2,
                                                   eidx, Wtw, bwf,
                                                   Wt1b, b_t1, Wt2b, b_t2, out);
}

// Round 8
// 111.368 us; speedup vs baseline: 1.0918x; 1.0918x over previous
//
#include <hip/hip_runtime.h>
#include <hip/hip_bf16.h>

#define N_NODES 8192
#define N_EDGES 131072
#define LN_EPS  1e-5f

typedef __attribute__((ext_vector_type(8))) short bf16x8;
typedef __attribute__((ext_vector_type(4))) float f32x4;

// silu via v_rcp_f32: avoids IEEE div expansion (no fast-math in harness)
__device__ __forceinline__ float silu_f(float x) {
    return x * __builtin_amdgcn_rcpf(1.0f + __expf(-x));
}

// fp32 -> bf16 RNE (scalar)
__device__ __forceinline__ unsigned short f2bf(float x) {
    union { float f; unsigned int u; } v; v.f = x;
    unsigned int r = v.u + 0x7FFFu + ((v.u >> 16) & 1u);
    return (unsigned short)(r >> 16);
}
__device__ __forceinline__ float bf2f(unsigned short u) {
    union { float f; unsigned int x; } v; v.x = ((unsigned int)u) << 16;
    return v.f;
}
// fp32 pair -> packed bf16x2 via v_cvt_pk_bf16_f32
__device__ __forceinline__ unsigned int pk2(float a, float b) {
    float2 t; t.x = a; t.y = b;
    union { __hip_bfloat162 h; unsigned int u; } v;
    v.h = __float22bfloat162_rn(t);
    return v.u;
}
__device__ __forceinline__ bf16x8 pack8(float4 u, float4 v) {
    union { bf16x8 b; unsigned int w[4]; } o;
    o.w[0] = pk2(u.x, u.y); o.w[1] = pk2(u.z, u.w);
    o.w[2] = pk2(v.x, v.y); o.w[3] = pk2(v.z, v.w);
    return o.b;
}
__device__ __forceinline__ f32x4 mfma16(bf16x8 a, bf16x8 b, f32x4 c) {
    return __builtin_amdgcn_mfma_f32_16x16x32_bf16(a, b, c, 0, 0, 0);
}

// ---------------------------------------------------------------------------
// Kernel 0: weight prep (round-6 verified).
// ---------------------------------------------------------------------------
__global__ __launch_bounds__(256) void prep_kernel(
    const float* __restrict__ W_w, const float* __restrict__ W_t1,
    const float* __restrict__ W_t2, const float* __restrict__ Wvq,
    const float* __restrict__ Wvk0, const float* __restrict__ Wvk1,
    const float* __restrict__ Wvk2,
    unsigned short* __restrict__ Wtw, unsigned short* __restrict__ Wt1b,
    unsigned short* __restrict__ Wt2b, unsigned short* __restrict__ Wqt,
    unsigned short* __restrict__ Wk0t, unsigned short* __restrict__ Wk1t,
    unsigned short* __restrict__ Wk2t)
{
    int i = blockIdx.x * 256 + threadIdx.x;
    if (i < 16384) {
        int n = i >> 7, k = i & 127;
        Wt1b[i] = f2bf(W_t1[k * 128 + n]);
        Wt2b[i] = f2bf(W_t2[k * 128 + n]);
    }
    if (i < 4096) {
        { int n = i >> 5, k = i & 31; Wtw[i] = f2bf(W_w[k * 128 + n]); }
        int r = i >> 7, d = i & 127;
        Wqt[i]  = f2bf(Wvq [d * 32 + r]);
        Wk0t[i] = f2bf(Wvk0[d * 32 + r]);
        Wk1t[i] = f2bf(Wvk1[d * 32 + r]);
        Wk2t[i] = f2bf(Wvk2[d * 32 + r]);
    }
}

// ---------------------------------------------------------------------------
// Kernel 1: MFMA projections (round-6 verified). [n][r][l16] output layout.
// ---------------------------------------------------------------------------
template<int S, int LOFF>
__device__ __forceinline__ void proj_body(
    const float* __restrict__ X, const unsigned short* __restrict__ Wqt,
    const unsigned short* __restrict__ Wkt,
    unsigned short* __restrict__ eq, unsigned short* __restrict__ ek,
    int row0)
{
    const int tid  = threadIdx.x;
    const int lane = tid & 63;
    const int wv   = tid >> 6;
    const int l15  = lane & 15;
    const int lk   = lane >> 4;
    const int xrow = row0 + wv * 16 + l15;

    bf16x8 xf[4];
    #pragma unroll
    for (int kt = 0; kt < 4; ++kt) {
        const float* p = X + (size_t)xrow * 128 + kt * 32 + lk * 8;
        xf[kt] = pack8(*(const float4*)p, *(const float4*)(p + 4));
    }

    f32x4 qa[2], ka[2];
    #pragma unroll
    for (int h = 0; h < 2; ++h) {
        qa[h] = (f32x4){0.f, 0.f, 0.f, 0.f};
        ka[h] = (f32x4){0.f, 0.f, 0.f, 0.f};
    }
    #pragma unroll
    for (int kt = 0; kt < 4; ++kt) {
        #pragma unroll
        for (int h = 0; h < 2; ++h) {
            bf16x8 wq = *(const bf16x8*)&Wqt[(h * 16 + l15) * 128 + kt * 32 + lk * 8];
            bf16x8 wk = *(const bf16x8*)&Wkt[(h * 16 + l15) * 128 + kt * 32 + lk * 8];
            qa[h] = mfma16(wq, xf[kt], qa[h]);
            ka[h] = mfma16(wk, xf[kt], ka[h]);
        }
    }

    const int n = xrow / S;
    const int l = xrow % S + LOFF;
    const size_t base = (size_t)n * 512 + l;   // [n][r][l16]
    #pragma unroll
    for (int h = 0; h < 2; ++h) {
        #pragma unroll
        for (int j = 0; j < 4; ++j) {
            const int r = h * 16 + lk * 4 + j;
            eq[base + r * 16] = f2bf(qa[h][j]);
            ek[base + r * 16] = f2bf(ka[h][j]);
        }
    }
}

__global__ __launch_bounds__(256) void proj_kernel(
    const float* __restrict__ X0, const float* __restrict__ X1,
    const float* __restrict__ X2,
    const unsigned short* __restrict__ Wqt,
    const unsigned short* __restrict__ Wk0t,
    const unsigned short* __restrict__ Wk1t,
    const unsigned short* __restrict__ Wk2t,
    unsigned short* __restrict__ eq, unsigned short* __restrict__ ek)
{
    const int b = blockIdx.x;
    if (b < 384)
        proj_body<3, 0>(X0, Wqt, Wk0t, eq, ek, b * 64);
    else if (b < 1024)
        proj_body<5, 3>(X1, Wqt, Wk1t, eq, ek, (b - 384) * 64);
    else
        proj_body<7, 8>(X2, Wqt, Wk2t, eq, ek, (b - 1024) * 64);
}

// ---------------------------------------------------------------------------
// Kernel 2: wn = LayerNorm(sum_l rej(q).rej(k)). 2 edges per thread for
// doubled gather MLP (8 independent 16B loads in flight). Rejection via the
// verified identity: w_r = q.k - (q.r)(k.r)(2 - r.r) per degree.
// ---------------------------------------------------------------------------
__device__ __forceinline__ float edge_w(
    bf16x8 q0, bf16x8 q1, bf16x8 k0, bf16x8 k1, const float* rv)
{
    float qv[15], kv[15];
    #pragma unroll
    for (int l = 0; l < 8; ++l) {
        qv[l] = bf2f((unsigned short)q0[l]);
        kv[l] = bf2f((unsigned short)k0[l]);
    }
    #pragma unroll
    for (int l = 8; l < 15; ++l) {
        qv[l] = bf2f((unsigned short)q1[l - 8]);
        kv[l] = bf2f((unsigned short)k1[l - 8]);
    }
    float qk = 0.f;
    #pragma unroll
    for (int l = 0; l < 15; ++l) qk = fmaf(qv[l], kv[l], qk);
    float c0 = 2.f, c1 = 2.f, c2 = 2.f;
    #pragma unroll
    for (int l = 0; l < 3; ++l)  c0 -= rv[l] * rv[l];
    #pragma unroll
    for (int l = 3; l < 8; ++l)  c1 -= rv[l] * rv[l];
    #pragma unroll
    for (int l = 8; l < 15; ++l) c2 -= rv[l] * rv[l];
    float dq0 = 0.f, dk0 = 0.f, dq1 = 0.f, dk1 = 0.f, dq2 = 0.f, dk2 = 0.f;
    #pragma unroll
    for (int l = 0; l < 3; ++l)  { dq0 = fmaf(qv[l], rv[l], dq0); dk0 = fmaf(kv[l], rv[l], dk0); }
    #pragma unroll
    for (int l = 3; l < 8; ++l)  { dq1 = fmaf(qv[l], rv[l], dq1); dk1 = fmaf(kv[l], rv[l], dk1); }
    #pragma unroll
    for (int l = 8; l < 15; ++l) { dq2 = fmaf(qv[l], rv[l], dq2); dk2 = fmaf(kv[l], rv[l], dk2); }
    return qk - dq0 * dk0 * c0 - dq1 * dk1 * c1 - dq2 * dk2 * c2;
}

__global__ __launch_bounds__(256) void wn_kernel(
    const unsigned short* __restrict__ eq, const unsigned short* __restrict__ ek,
    const float* __restrict__ r0, const float* __restrict__ r1,
    const float* __restrict__ r2, const int* __restrict__ eidx,
    const float* __restrict__ ln_g, const float* __restrict__ ln_b,
    unsigned short* __restrict__ wn)
{
    const int tid = threadIdx.x;
    const int r   = tid & 31;
    const int hw  = tid >> 5;
    const int e0  = blockIdx.x * 16 + hw * 2;
    const int e1  = e0 + 1;
    const float g  = ln_g[r];
    const float bb = ln_b[r];

    const int nj0 = eidx[e0], ni0 = eidx[N_EDGES + e0];
    const int nj1 = eidx[e1], ni1 = eidx[N_EDGES + e1];

    const unsigned short* qp0 = eq + (size_t)ni0 * 512 + r * 16;
    const unsigned short* kp0 = ek + (size_t)nj0 * 512 + r * 16;
    const unsigned short* qp1 = eq + (size_t)ni1 * 512 + r * 16;
    const unsigned short* kp1 = ek + (size_t)nj1 * 512 + r * 16;
    bf16x8 qa0 = *(const bf16x8*)qp0, qb0 = *(const bf16x8*)(qp0 + 8);
    bf16x8 ka0 = *(const bf16x8*)kp0, kb0 = *(const bf16x8*)(kp0 + 8);
    bf16x8 qa1 = *(const bf16x8*)qp1, qb1 = *(const bf16x8*)(qp1 + 8);
    bf16x8 ka1 = *(const bf16x8*)kp1, kb1 = *(const bf16x8*)(kp1 + 8);

    float rva[15], rvb[15];
    #pragma unroll
    for (int c = 0; c < 3; ++c) { rva[c]     = r0[e0 * 3 + c]; rvb[c]     = r0[e1 * 3 + c]; }
    #pragma unroll
    for (int c = 0; c < 5; ++c) { rva[3 + c] = r1[e0 * 5 + c]; rvb[3 + c] = r1[e1 * 5 + c]; }
    #pragma unroll
    for (int c = 0; c < 7; ++c) { rva[8 + c] = r2[e0 * 7 + c]; rvb[8 + c] = r2[e1 * 7 + c]; }

    const float w0 = edge_w(qa0, qb0, ka0, kb0, rva);
    const float w1 = edge_w(qa1, qb1, ka1, kb1, rvb);

    float s0 = w0, s20 = w0 * w0, s1 = w1, s21 = w1 * w1;
    #pragma unroll
    for (int off = 1; off < 32; off <<= 1) {
        s0  += __shfl_xor(s0,  off); s20 += __shfl_xor(s20, off);
        s1  += __shfl_xor(s1,  off); s21 += __shfl_xor(s21, off);
    }
    const float mu0   = s0 * (1.f / 32.f);
    const float var0  = s20 * (1.f / 32.f) - mu0 * mu0;
    const float mu1   = s1 * (1.f / 32.f);
    const float var1  = s21 * (1.f / 32.f) - mu1 * mu1;
    wn[(size_t)e0 * 32 + r] = f2bf((w0 - mu0) * rsqrtf(var0 + LN_EPS) * g + bb);
    wn[(size_t)e1 * 32 + r] = f2bf((w1 - mu1) * rsqrtf(var1 + LN_EPS) * g + bb);
}

// ---------------------------------------------------------------------------
// Kernel 3: barrier-free streaming MFMA GEMMs + epilogue, D[n][edge] layout.
// 64 edges/wave. ALL GEMM1 weight frags preloaded to registers before the
// MFMA phase, GEMM2 weight frags preloaded during the h-panel turnaround:
// converts 72 serialized L2-latency stalls into 2 pipelined bursts.
// __launch_bounds__(256,2): VGPR cap 256 (occupancy is LDS-capped at
// 2 blocks/CU anyway, so the registers are free).
// ---------------------------------------------------------------------------
__global__ __launch_bounds__(256, 2) void edge_kernel(
    const float* __restrict__ t_ij,
    const unsigned short* __restrict__ wn,
    const unsigned short* __restrict__ Wtw, const float* __restrict__ b_w,
    const unsigned short* __restrict__ Wt1, const float* __restrict__ b_t1,
    const unsigned short* __restrict__ Wt2, const float* __restrict__ b_t2,
    float* __restrict__ out)
{
    __shared__ __align__(16) unsigned short Hp[4][64 * 128];  // 16KB per wave

    const int tid  = threadIdx.x;
    const int lane = tid & 63;
    const int wv   = tid >> 6;
    const int l15  = lane & 15;
    const int lk   = lane >> 4;
    const int tile = (blockIdx.x * 4 + wv) * 64;
    char* hp = (char*)&Hp[wv][0];
    const int swz = (l15 & 7) << 4;

    // ---- B-frags: t_ij edges direct from global (lane = edge col) ----
    bf16x8 a1[4][4];
    #pragma unroll
    for (int kt = 0; kt < 4; ++kt)
        #pragma unroll
        for (int rt = 0; rt < 4; ++rt) {
            const float* p = t_ij + (size_t)(tile + rt * 16 + l15) * 128
                           + kt * 32 + lk * 8;
            a1[kt][rt] = pack8(*(const float4*)p, *(const float4*)(p + 4));
        }

    // ---- wn B-frags ----
    bf16x8 wnf[4];
    #pragma unroll
    for (int rt = 0; rt < 4; ++rt)
        wnf[rt] = *(const bf16x8*)&wn[(size_t)(tile + rt * 16 + l15) * 32 + lk * 8];

    // ---- preload ALL GEMM1 weight frags (32 x 4 VGPR) ----
    bf16x8 w1f[8][4];
    #pragma unroll
    for (int ct = 0; ct < 8; ++ct)
        #pragma unroll
        for (int kt = 0; kt < 4; ++kt)
            w1f[ct][kt] = *(const bf16x8*)&Wt1[(size_t)(ct * 16 + l15) * 128
                                               + kt * 32 + lk * 8];

    // ---- GEMM1: h = silu(t @ W_t1 + b_t1) -> D[n][edge] -> h panel ----
    #pragma unroll
    for (int ct = 0; ct < 8; ++ct) {
        f32x4 ac[4];
        #pragma unroll
        for (int rt = 0; rt < 4; ++rt) ac[rt] = (f32x4){0.f, 0.f, 0.f, 0.f};
        #pragma unroll
        for (int kt = 0; kt < 4; ++kt)
            #pragma unroll
            for (int rt = 0; rt < 4; ++rt)
                ac[rt] = mfma16(w1f[ct][kt], a1[kt][rt], ac[rt]);

        const float4 bt1 = *(const float4*)&b_t1[ct * 16 + lk * 4];
        #pragma unroll
        for (int rt = 0; rt < 4; ++rt) {
            uint2 hh;
            hh.x = pk2(silu_f(ac[rt][0] + bt1.x), silu_f(ac[rt][1] + bt1.y));
            hh.y = pk2(silu_f(ac[rt][2] + bt1.z), silu_f(ac[rt][3] + bt1.w));
            *(uint2*)(hp + (((rt * 16 + l15) * 256 + ct * 32 + lk * 8) ^ swz)) = hh;
        }
    }

    // ---- preload ALL GEMM2 weight frags while panel writes drain ----
    bf16x8 w2f[8][4];
    #pragma unroll
    for (int ct = 0; ct < 8; ++ct)
        #pragma unroll
        for (int kt = 0; kt < 4; ++kt)
            w2f[ct][kt] = *(const bf16x8*)&Wt2[(size_t)(ct * 16 + l15) * 128
                                               + kt * 32 + lk * 8];

    // ---- a2 B-frags from h panel (wave-local; compiler inserts lgkmcnt) ----
    bf16x8 a2[4][4];
    #pragma unroll
    for (int kt = 0; kt < 4; ++kt)
        #pragma unroll
        for (int rt = 0; rt < 4; ++rt)
            a2[kt][rt] = *(const bf16x8*)(hp +
                (((rt * 16 + l15) * 256 + kt * 64 + lk * 16) ^ swz));

    // ---- GEMM2 + dw + epilogue ----
    #pragma unroll
    for (int ct = 0; ct < 8; ++ct) {
        bf16x8 wwf = *(const bf16x8*)&Wtw[(ct * 16 + l15) * 32 + lk * 8];

        f32x4 o[4], d[4];
        #pragma unroll
        for (int rt = 0; rt < 4; ++rt) o[rt] = (f32x4){0.f, 0.f, 0.f, 0.f};
        #pragma unroll
        for (int kt = 0; kt < 4; ++kt)
            #pragma unroll
            for (int rt = 0; rt < 4; ++rt)
                o[rt] = mfma16(w2f[ct][kt], a2[kt][rt], o[rt]);
        #pragma unroll
        for (int rt = 0; rt < 4; ++rt)
            d[rt] = mfma16(wwf, wnf[rt], (f32x4){0.f, 0.f, 0.f, 0.f});

        const float4 bwv = *(const float4*)&b_w[ct * 16 + lk * 4];
        const float4 b2v = *(const float4*)&b_t2[ct * 16 + lk * 4];
        #pragma unroll
        for (int rt = 0; rt < 4; ++rt) {
            float4 s;
            s.x = (d[rt][0] + bwv.x) * silu_f(o[rt][0] + b2v.x);
            s.y = (d[rt][1] + bwv.y) * silu_f(o[rt][1] + b2v.y);
            s.z = (d[rt][2] + bwv.z) * silu_f(o[rt][2] + b2v.z);
            s.w = (d[rt][3] + bwv.w) * silu_f(o[rt][3] + b2v.w);
            *(float4*)&out[(size_t)(tile + rt * 16 + l15) * 128 + ct * 16 + lk * 4] = s;
        }
    }
}

extern "C" void kernel_launch(void* const* d_in, const int* in_sizes, int n_in,
                              void* d_out, int out_size, void* d_ws, size_t ws_size,
                              hipStream_t stream) {
    (void)in_sizes; (void)n_in; (void)out_size; (void)ws_size;
    const float* X0   = (const float*)d_in[0];
    const float* X1   = (const float*)d_in[1];
    const float* X2   = (const float*)d_in[2];
    const float* t_ij = (const float*)d_in[3];
    const float* r0   = (const float*)d_in[4];
    const float* r1   = (const float*)d_in[5];
    const float* r2   = (const float*)d_in[6];
    const int*   eidx = (const int*)d_in[7];
    const float* Wvq  = (const float*)d_in[8];
    const float* Wvk0 = (const float*)d_in[9];
    const float* Wvk1 = (const float*)d_in[10];
    const float* Wvk2 = (const float*)d_in[11];
    const float* ln_g = (const float*)d_in[12];
    const float* ln_b = (const float*)d_in[13];
    const float* W_w  = (const float*)d_in[14];
    const float* b_w  = (const float*)d_in[15];
    const float* W_t1 = (const float*)d_in[16];
    const float* b_t1 = (const float*)d_in[17];
    const float* W_t2 = (const float*)d_in[18];
    const float* b_t2 = (const float*)d_in[19];
    float* out = (float*)d_out;

    unsigned short* eq   = (unsigned short*)d_ws;          // [N][32][16] bf16
    unsigned short* ek   = eq  + (size_t)N_NODES * 512;
    unsigned short* wn   = ek  + (size_t)N_NODES * 512;    // [E,32] bf16
    unsigned short* Wtw  = wn  + (size_t)N_EDGES * 32;
    unsigned short* Wt1b = Wtw  + 4096;
    unsigned short* Wt2b = Wt1b + 16384;
    unsigned short* Wqt  = Wt2b + 16384;
    unsigned short* Wk0t = Wqt  + 4096;
    unsigned short* Wk1t = Wk0t + 4096;
    unsigned short* Wk2t = Wk1t + 4096;

    prep_kernel<<<64, 256, 0, stream>>>(W_w, W_t1, W_t2, Wvq, Wvk0, Wvk1, Wvk2,
                                        Wtw, Wt1b, Wt2b, Wqt, Wk0t, Wk1t, Wk2t);
    proj_kernel<<<1920, 256, 0, stream>>>(X0, X1, X2, Wqt, Wk0t, Wk1t, Wk2t,
                                          eq, ek);
    wn_kernel<<<N_EDGES / 16, 256, 0, stream>>>(eq, ek, r0, r1, r2, eidx,
                                                ln_g, ln_b, wn);
    edge_kernel<<<N_EDGES / 256, 256, 0, stream>>>(t_ij, wn, Wtw, b_w,
                                                   Wt1b, b_t1, Wt2b, b_t2, out);
}